// Round 1
// baseline (290.861 us; speedup 1.0000x reference)
//
#include <hip/hip_runtime.h>

#define N 12288
#define DIN 128
#define DOUT 64
#define LRELU_ALPHA 0.2f
#define STRIDE 65            // DOUT value columns + 1 scalar column
#define SCAN_PAD(k) ((k) + ((k) >> 5))   // LDS bank-conflict padding

// ---------- float ordered-int encoding for atomicMax on float ----------
__device__ __forceinline__ unsigned float_to_ordered(float x) {
    unsigned b = __float_as_uint(x);
    return (b & 0x80000000u) ? ~b : (b | 0x80000000u);
}
__device__ __forceinline__ float ordered_to_float(unsigned u) {
    unsigned b = (u & 0x80000000u) ? (u & 0x7FFFFFFFu) : ~u;
    return __uint_as_float(b);
}

// ---------- K1: Wh = h@W, s = Wh@a1, t = Wh@a2, T = max_j t_j ----------
__global__ __launch_bounds__(256) void k1_wh(
        const float* __restrict__ h, const float* __restrict__ W,
        const float* __restrict__ a, float* __restrict__ Wh,
        float* __restrict__ s, float* __restrict__ t,
        unsigned* __restrict__ tmax_ord) {
    __shared__ float Ws[DIN * DOUT];     // 32 KB
    __shared__ float as[2 * DOUT];
    __shared__ float hrow[4][DIN];
    int tid = threadIdx.x;
    for (int idx = tid; idx < DIN * DOUT; idx += 256) Ws[idx] = W[idx];
    if (tid < 2 * DOUT) as[tid] = a[tid];
    int wave = tid >> 6, lane = tid & 63;
    int i = blockIdx.x * 4 + wave;
    hrow[wave][lane]      = h[i * DIN + lane];
    hrow[wave][lane + 64] = h[i * DIN + 64 + lane];
    __syncthreads();
    float acc = 0.f;
    #pragma unroll 8
    for (int k = 0; k < DIN; ++k)
        acc = fmaf(hrow[wave][k], Ws[k * DOUT + lane], acc);
    Wh[i * DOUT + lane] = acc;
    float sv = acc * as[lane];
    float tv = acc * as[DOUT + lane];
    #pragma unroll
    for (int off = 32; off; off >>= 1) {
        sv += __shfl_down(sv, off, 64);
        tv += __shfl_down(tv, off, 64);
    }
    if (lane == 0) {
        s[i] = sv;
        t[i] = tv;
        atomicMax(tmax_ord, float_to_ordered(tv));
    }
}

// ---------- K2: rank[j] = #{j' : t[j'] < t[j] or (== and j' < j)} ----------
// grid (48, 8): blockIdx.x picks 256 j's, blockIdx.y a 1536-wide slice of j'.
__global__ __launch_bounds__(256) void k2_rank(
        const float* __restrict__ t, int* __restrict__ rank) {
    __shared__ float tt[1536];
    int j = blockIdx.x * 256 + threadIdx.x;
    int base0 = blockIdx.y * 1536;
    float tj = t[j];
    for (int e = threadIdx.x; e < 1536; e += 256) tt[e] = t[base0 + e];
    __syncthreads();
    int cnt = 0;
    for (int e = 0; e < 1536; ++e) {
        float tm = tt[e];
        cnt += (tm < tj || (tm == tj && (base0 + e) < j)) ? 1 : 0;
    }
    atomicAdd(&rank[j], cnt);
}

// ---------- K3: scatter weighted rows into sorted order ----------
__global__ __launch_bounds__(256) void k3_scatter(
        const float* __restrict__ Wh, const float* __restrict__ t,
        const int* __restrict__ rank, const unsigned* __restrict__ tmax_ord,
        float* __restrict__ V, float* __restrict__ U,
        float* __restrict__ tsort) {
    int tid = threadIdx.x;
    int wave = tid >> 6, lane = tid & 63;
    int j = blockIdx.x * 4 + wave;
    float T = ordered_to_float(*tmax_ord);
    float tj = t[j];
    int r = rank[j];
    float u = expf(tj - T);                   // positive-branch weight
    float v = expf(LRELU_ALPHA * (tj - T));   // negative-branch weight
    float w = Wh[j * DOUT + lane];
    V[r * STRIDE + lane] = v * w;
    U[r * STRIDE + lane] = u * w;
    if (lane == 0) {
        V[r * STRIDE + DOUT] = v;
        U[r * STRIDE + DOUT] = u;
        tsort[r] = tj;
    }
}

// ---------- K4: per-column scans, in place ----------
// blocks [0,65): forward EXCLUSIVE scan of V column (out[N] = total)
// blocks [65,130): suffix INCLUSIVE scan of U column (out[N] = 0)
__global__ __launch_bounds__(256) void k4_scan(
        float* __restrict__ V, float* __restrict__ U) {
    __shared__ float buf[N + (N >> 5)];   // padded, ~50 KB
    __shared__ float part[256];
    int b = blockIdx.x;
    bool fwd = b < STRIDE;
    float* arr = fwd ? V : U;
    int col = fwd ? b : b - STRIDE;
    int tid = threadIdx.x;
    // load column (reversed for the suffix scan)
    for (int k = tid; k < N; k += 256) {
        int src = fwd ? k : (N - 1 - k);
        buf[SCAN_PAD(k)] = arr[src * STRIDE + col];
    }
    __syncthreads();
    const int C = N / 256;  // 48
    float sum = 0.f;
    for (int e = 0; e < C; ++e) sum += buf[SCAN_PAD(tid * C + e)];
    part[tid] = sum;
    __syncthreads();
    for (int off = 1; off < 256; off <<= 1) {
        float v = part[tid];
        if (tid >= off) v += part[tid - off];
        __syncthreads();
        part[tid] = v;
        __syncthreads();
    }
    float running = (tid == 0) ? 0.f : part[tid - 1];
    if (fwd) {
        for (int e = 0; e < C; ++e) {
            int idx = tid * C + e;
            float old = buf[SCAN_PAD(idx)];
            arr[idx * STRIDE + col] = running;   // exclusive prefix
            running += old;
        }
        if (tid == 255) arr[N * STRIDE + col] = running;  // total
    } else {
        for (int e = 0; e < C; ++e) {
            int idx = tid * C + e;
            running += buf[SCAN_PAD(idx)];
            arr[(N - 1 - idx) * STRIDE + col] = running;  // inclusive suffix
        }
        if (tid == 0) arr[N * STRIDE + col] = 0.f;
    }
}

// ---------- K5: binary search + combine + ELU ----------
__global__ __launch_bounds__(256) void k5_out(
        const float* __restrict__ s, const float* __restrict__ tsort,
        const float* __restrict__ V, const float* __restrict__ U,
        const unsigned* __restrict__ tmax_ord, float* __restrict__ out) {
    int tid = threadIdx.x;
    int wave = tid >> 6, lane = tid & 63;
    int i = blockIdx.x * 4 + wave;
    float T = ordered_to_float(*tmax_ord);
    float si = s[i];
    float thr = -si;
    int lo = 0, hi = N;
    while (lo < hi) {               // lower_bound: first k with tsort[k] >= thr
        int mid = (lo + hi) >> 1;
        if (tsort[mid] < thr) lo = mid + 1; else hi = mid;
    }
    int k = lo;                      // ranks < k: negative branch; >= k: positive
    float x = si + T;
    float m = x > 0.f ? x : LRELU_ALPHA * x;          // row max of e
    float c_pos = expf(x - m);                        // <= 1
    float c_neg = expf(LRELU_ALPHA * x - m);          // <= 1
    const float* Vr = V + (size_t)k * STRIDE;
    const float* Ur = U + (size_t)k * STRIDE;
    float den = c_neg * Vr[DOUT] + c_pos * Ur[DOUT];  // >= 1 by construction
    float num = c_neg * Vr[lane] + c_pos * Ur[lane];
    float r = num / den;
    out[i * DOUT + lane] = r > 0.f ? r : expm1f(r);   // ELU(alpha=1)
}

extern "C" void kernel_launch(void* const* d_in, const int* in_sizes, int n_in,
                              void* d_out, int out_size, void* d_ws, size_t ws_size,
                              hipStream_t stream) {
    const float* h = (const float*)d_in[0];
    const float* W = (const float*)d_in[1];
    const float* a = (const float*)d_in[2];
    float* out = (float*)d_out;

    float* ws    = (float*)d_ws;
    float* Wh    = ws + 16;              // header: 16 floats (tmax at [0])
    float* s     = Wh + (size_t)N * DOUT;
    float* t     = s + N;
    float* tsort = t + N;
    int*   rank  = (int*)(tsort + N);
    float* V     = (float*)(rank + N);
    float* U     = V + (size_t)(N + 1) * STRIDE;
    unsigned* hdr = (unsigned*)ws;
    // total ws use: ~9.8 MB

    hipMemsetAsync(hdr, 0, 64, stream);               // T ordered-max init
    hipMemsetAsync(rank, 0, N * sizeof(int), stream); // rank accumulators

    k1_wh<<<N / 4, 256, 0, stream>>>(h, W, a, Wh, s, t, hdr);
    dim3 g2(48, 8);
    k2_rank<<<g2, 256, 0, stream>>>(t, rank);
    k3_scatter<<<N / 4, 256, 0, stream>>>(Wh, t, rank, hdr, V, U, tsort);
    k4_scan<<<2 * STRIDE, 256, 0, stream>>>(V, U);
    k5_out<<<N / 4, 256, 0, stream>>>(s, tsort, V, U, hdr, out);
}

// Round 2
// 170.870 us; speedup vs baseline: 1.7022x; 1.7022x over previous
//
#include <hip/hip_runtime.h>

#define N 12288
#define DIN 128
#define DOUT 64
#define LRELU_ALPHA 0.2f
#define STRIDE 65            // DOUT value columns + 1 scalar column
#define SCAN_PAD(k) ((k) + ((k) >> 5))   // LDS bank-conflict padding

// ---------- K1: Wh = h@W, s = Wh@a1, t = Wh@a2 (NO atomics) ----------
// 384 blocks x 256 threads; each wave handles 8 rows held in registers,
// broadcast per-k via shfl (readlane). One ds_read of W row per k per wave.
__global__ __launch_bounds__(256) void k1_wh(
        const float* __restrict__ h, const float* __restrict__ W,
        const float* __restrict__ a, float* __restrict__ Wh,
        float* __restrict__ s, float* __restrict__ t) {
    __shared__ float Ws[DIN * DOUT];     // 32 KB
    __shared__ float as[2 * DOUT];
    int tid = threadIdx.x;
    int wave = tid >> 6, lane = tid & 63;
    // stage W (vectorized) and a
    const float4* W4 = (const float4*)W;
    float4* Ws4 = (float4*)Ws;
    for (int idx = tid; idx < DIN * DOUT / 4; idx += 256) Ws4[idx] = W4[idx];
    if (tid < 2 * DOUT) as[tid] = a[tid];
    int row0 = blockIdx.x * 32 + wave * 8;
    // 8 rows of h in registers: h0 = cols [0,64), h1 = cols [64,128)
    float h0[8], h1[8];
    #pragma unroll
    for (int r = 0; r < 8; ++r) {
        h0[r] = h[(size_t)(row0 + r) * DIN + lane];
        h1[r] = h[(size_t)(row0 + r) * DIN + 64 + lane];
    }
    __syncthreads();
    float acc[8];
    #pragma unroll
    for (int r = 0; r < 8; ++r) acc[r] = 0.f;
    for (int k = 0; k < 64; ++k) {
        float wv = Ws[k * DOUT + lane];
        #pragma unroll
        for (int r = 0; r < 8; ++r)
            acc[r] = fmaf(__shfl(h0[r], k, 64), wv, acc[r]);
    }
    for (int k = 0; k < 64; ++k) {
        float wv = Ws[(k + 64) * DOUT + lane];
        #pragma unroll
        for (int r = 0; r < 8; ++r)
            acc[r] = fmaf(__shfl(h1[r], k, 64), wv, acc[r]);
    }
    float a1 = as[lane], a2 = as[DOUT + lane];
    #pragma unroll
    for (int r = 0; r < 8; ++r) {
        Wh[(size_t)(row0 + r) * DOUT + lane] = acc[r];
        float sv = acc[r] * a1;
        float tv = acc[r] * a2;
        #pragma unroll
        for (int off = 32; off; off >>= 1) {
            sv += __shfl_down(sv, off, 64);
            tv += __shfl_down(tv, off, 64);
        }
        if (lane == 0) { s[row0 + r] = sv; t[row0 + r] = tv; }
    }
}

// ---------- K1b: T = max_j t[j]; also zero rank accumulators ----------
__global__ __launch_bounds__(1024) void k1b_max(
        const float* __restrict__ t, float* __restrict__ T,
        int* __restrict__ rank) {
    __shared__ float wmax[16];
    int tid = threadIdx.x;
    float m = -1e30f;
    for (int e = tid; e < N; e += 1024) {
        m = fmaxf(m, t[e]);
        rank[e] = 0;
    }
    #pragma unroll
    for (int off = 32; off; off >>= 1) m = fmaxf(m, __shfl_down(m, off, 64));
    if ((tid & 63) == 0) wmax[tid >> 6] = m;
    __syncthreads();
    if (tid == 0) {
        float mm = wmax[0];
        for (int w = 1; w < 16; ++w) mm = fmaxf(mm, wmax[w]);
        T[0] = mm;
    }
}

// ---------- K2: rank[j] = #{j' : t[j'] < t[j] or (== and j' < j)} ----------
// grid (48, 16); j' tile streams through registers, broadcast via shfl.
__global__ __launch_bounds__(256) void k2_rank(
        const float* __restrict__ t, int* __restrict__ rank) {
    int tid = threadIdx.x, lane = tid & 63;
    int j = blockIdx.x * 256 + tid;
    const int SLICE = N / 16;   // 768
    int base = blockIdx.y * SLICE;
    float tj = t[j];
    int cnt = 0;
    for (int e0 = 0; e0 < SLICE; e0 += 64) {
        float tl = t[base + e0 + lane];     // coalesced
        #pragma unroll
        for (int l = 0; l < 64; ++l) {
            float tm = __shfl(tl, l, 64);   // wave-uniform broadcast
            int jp = base + e0 + l;
            cnt += (tm < tj || (tm == tj && jp < j)) ? 1 : 0;
        }
    }
    atomicAdd(&rank[j], cnt);   // 12288 distinct addresses — uncontended
}

// ---------- K3: scatter weighted rows into sorted order ----------
__global__ __launch_bounds__(256) void k3_scatter(
        const float* __restrict__ Wh, const float* __restrict__ t,
        const int* __restrict__ rank, const float* __restrict__ T,
        float* __restrict__ V, float* __restrict__ U,
        float* __restrict__ tsort) {
    int tid = threadIdx.x;
    int wave = tid >> 6, lane = tid & 63;
    int j = blockIdx.x * 4 + wave;
    float Tm = *T;
    float tj = t[j];
    int r = rank[j];
    float u = expf(tj - Tm);                   // positive-branch weight
    float v = expf(LRELU_ALPHA * (tj - Tm));   // negative-branch weight
    float w = Wh[(size_t)j * DOUT + lane];
    V[(size_t)r * STRIDE + lane] = v * w;
    U[(size_t)r * STRIDE + lane] = u * w;
    if (lane == 0) {
        V[(size_t)r * STRIDE + DOUT] = v;
        U[(size_t)r * STRIDE + DOUT] = u;
        tsort[r] = tj;
    }
}

// ---------- K4: per-column scans, in place ----------
// blocks [0,65): forward EXCLUSIVE scan of V column (out[N] = total)
// blocks [65,130): suffix INCLUSIVE scan of U column (out[N] = 0)
__global__ __launch_bounds__(256) void k4_scan(
        float* __restrict__ V, float* __restrict__ U) {
    __shared__ float buf[N + (N >> 5)];   // padded, ~50 KB
    __shared__ float wtot[4];
    int b = blockIdx.x;
    bool fwd = b < STRIDE;
    float* arr = fwd ? V : U;
    int col = fwd ? b : b - STRIDE;
    int tid = threadIdx.x, lane = tid & 63, wave = tid >> 6;
    for (int k = tid; k < N; k += 256) {
        int src = fwd ? k : (N - 1 - k);
        buf[SCAN_PAD(k)] = arr[(size_t)src * STRIDE + col];
    }
    __syncthreads();
    const int C = N / 256;  // 48
    float sum = 0.f;
    for (int e = 0; e < C; ++e) sum += buf[SCAN_PAD(tid * C + e)];
    float mysum = sum;
    // wave-level inclusive scan (no barriers)
    #pragma unroll
    for (int off = 1; off < 64; off <<= 1) {
        float nb = __shfl_up(sum, off, 64);
        if (lane >= off) sum += nb;
    }
    if (lane == 63) wtot[wave] = sum;
    __syncthreads();
    float add = 0.f;
    #pragma unroll
    for (int w = 0; w < 4; ++w) add += (w < wave) ? wtot[w] : 0.f;
    float running = add + sum - mysum;   // exclusive prefix of this thread's chunk
    if (fwd) {
        for (int e = 0; e < C; ++e) {
            int idx = tid * C + e;
            float old = buf[SCAN_PAD(idx)];
            arr[(size_t)idx * STRIDE + col] = running;   // exclusive prefix
            running += old;
        }
        if (tid == 255) arr[(size_t)N * STRIDE + col] = running;  // total
    } else {
        for (int e = 0; e < C; ++e) {
            int idx = tid * C + e;
            running += buf[SCAN_PAD(idx)];
            arr[(size_t)(N - 1 - idx) * STRIDE + col] = running;  // inclusive suffix
        }
        if (tid == 0) arr[(size_t)N * STRIDE + col] = 0.f;
    }
}

// ---------- K5: binary search + combine + ELU ----------
__global__ __launch_bounds__(256) void k5_out(
        const float* __restrict__ s, const float* __restrict__ tsort,
        const float* __restrict__ V, const float* __restrict__ U,
        const float* __restrict__ T, float* __restrict__ out) {
    int tid = threadIdx.x;
    int wave = tid >> 6, lane = tid & 63;
    int i = blockIdx.x * 4 + wave;
    float Tm = *T;
    float si = s[i];
    float thr = -si;
    int lo = 0, hi = N;
    while (lo < hi) {               // lower_bound: first k with tsort[k] >= thr
        int mid = (lo + hi) >> 1;
        if (tsort[mid] < thr) lo = mid + 1; else hi = mid;
    }
    int k = lo;                      // ranks < k: negative branch; >= k: positive
    float x = si + Tm;
    float m = x > 0.f ? x : LRELU_ALPHA * x;          // row max of e
    float c_pos = expf(x - m);                        // <= 1
    float c_neg = expf(LRELU_ALPHA * x - m);          // <= 1
    const float* Vr = V + (size_t)k * STRIDE;
    const float* Ur = U + (size_t)k * STRIDE;
    float den = c_neg * Vr[DOUT] + c_pos * Ur[DOUT];  // >= 1 by construction
    float num = c_neg * Vr[lane] + c_pos * Ur[lane];
    float r = num / den;
    out[(size_t)i * DOUT + lane] = r > 0.f ? r : expm1f(r);   // ELU(alpha=1)
}

extern "C" void kernel_launch(void* const* d_in, const int* in_sizes, int n_in,
                              void* d_out, int out_size, void* d_ws, size_t ws_size,
                              hipStream_t stream) {
    const float* h = (const float*)d_in[0];
    const float* W = (const float*)d_in[1];
    const float* a = (const float*)d_in[2];
    float* out = (float*)d_out;

    float* ws    = (float*)d_ws;
    float* T     = ws;                   // header: 16 floats (T at [0])
    float* Wh    = ws + 16;
    float* s     = Wh + (size_t)N * DOUT;
    float* t     = s + N;
    float* tsort = t + N;
    int*   rank  = (int*)(tsort + N);
    float* V     = (float*)(rank + N);
    float* U     = V + (size_t)(N + 1) * STRIDE;
    // total ws use: ~9.8 MB

    k1_wh<<<N / 32, 256, 0, stream>>>(h, W, a, Wh, s, t);
    k1b_max<<<1, 1024, 0, stream>>>(t, T, rank);
    dim3 g2(48, 16);
    k2_rank<<<g2, 256, 0, stream>>>(t, rank);
    k3_scatter<<<N / 4, 256, 0, stream>>>(Wh, t, rank, T, V, U, tsort);
    k4_scan<<<2 * STRIDE, 256, 0, stream>>>(V, U);
    k5_out<<<N / 4, 256, 0, stream>>>(s, tsort, V, U, T, out);
}

// Round 3
// 143.648 us; speedup vs baseline: 2.0248x; 1.1895x over previous
//
#include <hip/hip_runtime.h>

#define N 12288
#define DIN 128
#define DOUT 64
#define NBIN 8192
#define NCH 384            // chunks of 32 rows

// monotone float -> bin (order-preserving bit transform, top 13 bits)
__device__ __forceinline__ int t_bin(float x) {
    unsigned b = __float_as_uint(x);
    unsigned o = (b & 0x80000000u) ? ~b : (b | 0x80000000u);
    return (int)(o >> 19);
}

// ---------- K1: Wh = h@W, s = Wh@a1, t = Wh@a2 ----------
// 384 blocks x 128 threads (2 waves x 16 rows). Thread: 4 rows x 4 cols,
// k-blocked by 4 -> all LDS reads are ds_read_b128, no bpermute.
__global__ __launch_bounds__(128) void k1_wh(
        const float* __restrict__ h, const float* __restrict__ W,
        const float* __restrict__ a, float* __restrict__ Wh,
        float* __restrict__ s, float* __restrict__ t) {
    __shared__ float4 Ws4[DIN * 16];   // W[k][c] as float4 over c  (32 KB)
    __shared__ float4 hs4[32 * 32];    // h[r][k] as float4 over k  (16 KB)
    int tid = threadIdx.x, wave = tid >> 6, lane = tid & 63;
    int row0 = blockIdx.x * 32;
    const float4* W4 = (const float4*)W;
    #pragma unroll
    for (int e = tid; e < DIN * 16; e += 128) Ws4[e] = W4[e];
    const float4* h4 = (const float4*)(h + (size_t)row0 * DIN);
    #pragma unroll
    for (int e = tid; e < 32 * 32; e += 128) hs4[e] = h4[e];
    __syncthreads();
    int c0 = lane & 15, rq = lane >> 4;
    int rbase = wave * 16 + rq * 4;          // 4 rows rbase..rbase+3
    float4 acc[4];
    #pragma unroll
    for (int rr = 0; rr < 4; ++rr) acc[rr] = make_float4(0.f, 0.f, 0.f, 0.f);
    #pragma unroll 2
    for (int kk = 0; kk < 32; ++kk) {
        float4 w0 = Ws4[(4 * kk + 0) * 16 + c0];
        float4 w1 = Ws4[(4 * kk + 1) * 16 + c0];
        float4 w2 = Ws4[(4 * kk + 2) * 16 + c0];
        float4 w3 = Ws4[(4 * kk + 3) * 16 + c0];
        #pragma unroll
        for (int rr = 0; rr < 4; ++rr) {
            float4 hv = hs4[(rbase + rr) * 32 + kk];
            acc[rr].x = fmaf(hv.x, w0.x, acc[rr].x);
            acc[rr].y = fmaf(hv.x, w0.y, acc[rr].y);
            acc[rr].z = fmaf(hv.x, w0.z, acc[rr].z);
            acc[rr].w = fmaf(hv.x, w0.w, acc[rr].w);
            acc[rr].x = fmaf(hv.y, w1.x, acc[rr].x);
            acc[rr].y = fmaf(hv.y, w1.y, acc[rr].y);
            acc[rr].z = fmaf(hv.y, w1.z, acc[rr].z);
            acc[rr].w = fmaf(hv.y, w1.w, acc[rr].w);
            acc[rr].x = fmaf(hv.z, w2.x, acc[rr].x);
            acc[rr].y = fmaf(hv.z, w2.y, acc[rr].y);
            acc[rr].z = fmaf(hv.z, w2.z, acc[rr].z);
            acc[rr].w = fmaf(hv.z, w2.w, acc[rr].w);
            acc[rr].x = fmaf(hv.w, w3.x, acc[rr].x);
            acc[rr].y = fmaf(hv.w, w3.y, acc[rr].y);
            acc[rr].z = fmaf(hv.w, w3.z, acc[rr].z);
            acc[rr].w = fmaf(hv.w, w3.w, acc[rr].w);
        }
    }
    float4 a1 = ((const float4*)a)[c0];
    float4 a2 = ((const float4*)a)[16 + c0];
    #pragma unroll
    for (int rr = 0; rr < 4; ++rr) {
        int row = row0 + rbase + rr;
        ((float4*)Wh)[(size_t)row * 16 + c0] = acc[rr];
        float sv = acc[rr].x * a1.x + acc[rr].y * a1.y + acc[rr].z * a1.z + acc[rr].w * a1.w;
        float tv = acc[rr].x * a2.x + acc[rr].y * a2.y + acc[rr].z * a2.z + acc[rr].w * a2.w;
        #pragma unroll
        for (int off = 8; off; off >>= 1) {   // reduce over the 16 c0 lanes
            sv += __shfl_xor(sv, off, 64);
            tv += __shfl_xor(tv, off, 64);
        }
        if (c0 == 0) { s[row] = sv; t[row] = tv; }
    }
}

// ---------- K2ab: LDS histogram + exclusive scan -> binstart; zero binoff ----
__global__ __launch_bounds__(1024) void k2ab(
        const float* __restrict__ t, int* __restrict__ binstart,
        int* __restrict__ binoff) {
    __shared__ int hist[NBIN];          // 32 KB
    __shared__ int wtot[16];
    int tid = threadIdx.x;
    #pragma unroll
    for (int e = tid; e < NBIN; e += 1024) hist[e] = 0;
    __syncthreads();
    for (int e = tid; e < N; e += 1024) atomicAdd(&hist[t_bin(t[e])], 1);
    __syncthreads();
    int base = tid * 8;
    int csum[8]; int sum = 0;
    #pragma unroll
    for (int e = 0; e < 8; ++e) { csum[e] = sum; sum += hist[base + e]; }
    int lane = tid & 63, wave = tid >> 6;
    int inc = sum;
    #pragma unroll
    for (int off = 1; off < 64; off <<= 1) {
        int nbr = __shfl_up(inc, off, 64);
        if (lane >= off) inc += nbr;
    }
    if (lane == 63) wtot[wave] = inc;
    __syncthreads();
    int wbase = 0;
    #pragma unroll
    for (int w = 0; w < 16; ++w) wbase += (w < wave) ? wtot[w] : 0;
    int tstart = wbase + inc - sum;      // exclusive prefix for this thread
    #pragma unroll
    for (int e = 0; e < 8; ++e) binstart[base + e] = tstart + csum[e];
    if (tid == 0) binstart[NBIN] = N;
    for (int e = tid; e < NBIN; e += 1024) binoff[e] = 0;
}

// ---------- K2c: scatter into bin-grouped order ----------
__global__ __launch_bounds__(1024) void k2c(
        const float* __restrict__ t, const int* __restrict__ binstart,
        int* __restrict__ binoff, int* __restrict__ ordarr,
        float* __restrict__ tscat) {
    int j = blockIdx.x * 1024 + threadIdx.x;
    float tj = t[j];
    int b = t_bin(tj);
    int pos = binstart[b] + atomicAdd(&binoff[b], 1);
    ordarr[pos] = j;
    tscat[pos] = tj;
}

// ---------- K3: exact within-bin rank -> value-sorted tfin / ordfin ----------
__global__ __launch_bounds__(1024) void k3_rank(
        const int* __restrict__ binstart, const int* __restrict__ ordarr,
        const float* __restrict__ tscat, float* __restrict__ tfin,
        int* __restrict__ ordfin) {
    int p = blockIdx.x * 1024 + threadIdx.x;
    float tp = tscat[p];
    int b = t_bin(tp);
    int lo = binstart[b], hi = binstart[b + 1];
    int cnt = 0;
    for (int q = lo; q < hi; ++q) {
        float tq = tscat[q];
        cnt += (tq < tp || (tq == tp && q < p)) ? 1 : 0;
    }
    int r = lo + cnt;
    tfin[r] = tp;
    ordfin[r] = ordarr[p];
}

// ---------- K4a: per-chunk (32 rows) column sums, gathered from Wh ----------
__global__ __launch_bounds__(256) void k4a(
        const float* __restrict__ Wh, const float* __restrict__ tfin,
        const int* __restrict__ ordfin, float* __restrict__ Vct,
        float* __restrict__ Uct, float* __restrict__ vsc,
        float* __restrict__ usc) {
    __shared__ float lv[4][64], lu[4][64];
    __shared__ float lsv[4], lsu[4];
    int tid = threadIdx.x, wave = tid >> 6, lane = tid & 63;
    int chunk = blockIdx.x;
    float T = tfin[N - 1];
    int r0 = chunk * 32 + wave * 8;
    float av = 0.f, au = 0.f, asv = 0.f, asu = 0.f;
    #pragma unroll
    for (int rr = 0; rr < 8; ++rr) {
        int row = r0 + rr;
        int j = ordfin[row];
        float tv = tfin[row];
        float u = expf(tv - T);
        float v = expf(0.2f * (tv - T));
        float wv = Wh[(size_t)j * DOUT + lane];
        av = fmaf(v, wv, av); au = fmaf(u, wv, au);
        asv += v; asu += u;
    }
    lv[wave][lane] = av; lu[wave][lane] = au;
    if (lane == 0) { lsv[wave] = asv; lsu[wave] = asu; }
    __syncthreads();
    if (wave == 0) {
        float sv_ = lv[0][lane] + lv[1][lane] + lv[2][lane] + lv[3][lane];
        float su_ = lu[0][lane] + lu[1][lane] + lu[2][lane] + lu[3][lane];
        Vct[lane * NCH + chunk] = sv_;        // transposed: contiguous per col
        Uct[lane * NCH + chunk] = su_;
        if (lane == 0) {
            vsc[chunk] = lsv[0] + lsv[1] + lsv[2] + lsv[3];
            usc[chunk] = lsu[0] + lsu[1] + lsu[2] + lsu[3];
        }
    }
}

// ---------- K4b: scan chunk sums (V fwd-exclusive, U suffix) + totals -------
__global__ __launch_bounds__(256) void k4b(
        const float* __restrict__ Vct, const float* __restrict__ Uct,
        const float* __restrict__ vsc, const float* __restrict__ usc,
        float* __restrict__ basevt, float* __restrict__ baseut,
        float* __restrict__ basevs, float* __restrict__ baseus,
        float* __restrict__ Vexc, float* __restrict__ Usuf,
        float* __restrict__ vsexc, float* __restrict__ ussuf) {
    int tid = threadIdx.x;
    if (tid < 64) {                       // V columns, forward exclusive
        const float* src = Vct + tid * NCH;
        float* dst = basevt + tid * NCH;
        float run = 0.f;
        for (int c = 0; c < NCH; ++c) { dst[c] = run; run += src[c]; }
        Vexc[(size_t)N * DOUT + tid] = run;   // total
        Usuf[(size_t)N * DOUT + tid] = 0.f;
    } else if (tid < 128) {               // U columns, suffix-exclusive base
        int c0 = tid - 64;
        const float* src = Uct + c0 * NCH;
        float* dst = baseut + c0 * NCH;
        float run = 0.f;
        for (int c = NCH - 1; c >= 0; --c) { dst[c] = run; run += src[c]; }
    } else if (tid == 128) {
        float run = 0.f;
        for (int c = 0; c < NCH; ++c) { basevs[c] = run; run += vsc[c]; }
        vsexc[N] = run; ussuf[N] = 0.f;
    } else if (tid == 129) {
        float run = 0.f;
        for (int c = NCH - 1; c >= 0; --c) { baseus[c] = run; run += usc[c]; }
    }
}

// ---------- K4c: apply within-chunk running sums, write Vexc/Usuf -----------
__global__ __launch_bounds__(128) void k4c(
        const float* __restrict__ Wh, const float* __restrict__ tfin,
        const int* __restrict__ ordfin, const float* __restrict__ basevt,
        const float* __restrict__ baseut, const float* __restrict__ basevs,
        const float* __restrict__ baseus, float* __restrict__ Vexc,
        float* __restrict__ Usuf, float* __restrict__ vsexc,
        float* __restrict__ ussuf) {
    int tid = threadIdx.x, wave = tid >> 6, lane = tid & 63;
    int chunk = blockIdx.x;
    int r0 = chunk * 32;
    float T = tfin[N - 1];
    float wv[32], wt[32];
    #pragma unroll
    for (int rr = 0; rr < 32; ++rr) {
        int j = ordfin[r0 + rr];
        wv[rr] = Wh[(size_t)j * DOUT + lane];
        float tv = tfin[r0 + rr];
        wt[rr] = (wave == 0) ? expf(0.2f * (tv - T)) : expf(tv - T);
    }
    if (wave == 0) {                       // V: forward exclusive
        float run = basevt[lane * NCH + chunk];
        float runs = basevs[chunk];
        #pragma unroll
        for (int rr = 0; rr < 32; ++rr) {
            int row = r0 + rr;
            Vexc[(size_t)row * DOUT + lane] = run;
            if (lane == 0) vsexc[row] = runs;
            run = fmaf(wt[rr], wv[rr], run);
            runs += wt[rr];
        }
    } else {                               // U: suffix inclusive
        float run = baseut[lane * NCH + chunk];
        float runs = baseus[chunk];
        #pragma unroll
        for (int rr = 31; rr >= 0; --rr) {
            int row = r0 + rr;
            run = fmaf(wt[rr], wv[rr], run);
            runs += wt[rr];
            Usuf[(size_t)row * DOUT + lane] = run;
            if (lane == 0) ussuf[row] = runs;
        }
    }
}

// ---------- K5: bin-seeded binary search + combine + ELU ----------
__global__ __launch_bounds__(256) void k5_out(
        const float* __restrict__ s, const float* __restrict__ tfin,
        const int* __restrict__ binstart, const float* __restrict__ Vexc,
        const float* __restrict__ Usuf, const float* __restrict__ vsexc,
        const float* __restrict__ ussuf, float* __restrict__ out) {
    int tid = threadIdx.x, wave = tid >> 6, lane = tid & 63;
    int i = blockIdx.x * 4 + wave;
    float T = tfin[N - 1];
    float si = s[i];
    float thr = -si;
    int b = t_bin(thr);
    int lo = binstart[b], hi = binstart[b + 1];
    while (lo < hi) {                     // lower_bound within the bin
        int mid = (lo + hi) >> 1;
        if (tfin[mid] < thr) lo = mid + 1; else hi = mid;
    }
    int k = lo;                           // ranks < k: negative branch
    float x = si + T;
    float m = fmaxf(x, 0.2f * x);         // lrelu(x) = row max of e
    float c_pos = expf(x - m);
    float c_neg = expf(0.2f * x - m);
    float den = c_neg * vsexc[k] + c_pos * ussuf[k];
    float num = c_neg * Vexc[(size_t)k * DOUT + lane]
              + c_pos * Usuf[(size_t)k * DOUT + lane];
    float r = num / den;
    out[(size_t)i * DOUT + lane] = r > 0.f ? r : expm1f(r);
}

extern "C" void kernel_launch(void* const* d_in, const int* in_sizes, int n_in,
                              void* d_out, int out_size, void* d_ws, size_t ws_size,
                              hipStream_t stream) {
    const float* h = (const float*)d_in[0];
    const float* W = (const float*)d_in[1];
    const float* a = (const float*)d_in[2];
    float* out = (float*)d_out;

    float* ws = (float*)d_ws;
    size_t o = 0;
    float* Wh     = ws + o; o += (size_t)N * DOUT;        // 786432
    float* Vexc   = ws + o; o += (size_t)(N + 1) * DOUT;  // 786496
    float* Usuf   = ws + o; o += (size_t)(N + 1) * DOUT;
    float* s      = ws + o; o += N;
    float* t      = ws + o; o += N;
    float* tscat  = ws + o; o += N;
    float* tfin   = ws + o; o += N;
    float* vsexc  = ws + o; o += N + 1;
    float* ussuf  = ws + o; o += N + 1;
    o += 2;                                               // alignment pad
    float* Vct    = ws + o; o += (size_t)DOUT * NCH;
    float* Uct    = ws + o; o += (size_t)DOUT * NCH;
    float* basevt = ws + o; o += (size_t)DOUT * NCH;
    float* baseut = ws + o; o += (size_t)DOUT * NCH;
    float* vsc    = ws + o; o += NCH;
    float* usc    = ws + o; o += NCH;
    float* basevs = ws + o; o += NCH;
    float* baseus = ws + o; o += NCH;
    int* binstart = (int*)(ws + o); o += NBIN + 1;
    int* binoff   = (int*)(ws + o); o += NBIN;
    int* ordarr   = (int*)(ws + o); o += N;
    int* ordfin   = (int*)(ws + o); o += N;
    // ~10.4 MB total

    k1_wh <<<N / 32, 128, 0, stream>>>(h, W, a, Wh, s, t);
    k2ab  <<<1, 1024, 0, stream>>>(t, binstart, binoff);
    k2c   <<<N / 1024, 1024, 0, stream>>>(t, binstart, binoff, ordarr, tscat);
    k3_rank<<<N / 1024, 1024, 0, stream>>>(binstart, ordarr, tscat, tfin, ordfin);
    k4a   <<<NCH, 256, 0, stream>>>(Wh, tfin, ordfin, Vct, Uct, vsc, usc);
    k4b   <<<1, 256, 0, stream>>>(Vct, Uct, vsc, usc, basevt, baseut, basevs,
                                  baseus, Vexc, Usuf, vsexc, ussuf);
    k4c   <<<NCH, 128, 0, stream>>>(Wh, tfin, ordfin, basevt, baseut, basevs,
                                    baseus, Vexc, Usuf, vsexc, ussuf);
    k5_out<<<N / 4, 256, 0, stream>>>(s, tfin, binstart, Vexc, Usuf, vsexc,
                                      ussuf, out);
}